// Round 3
// baseline (923.279 us; speedup 1.0000x reference)
//
#include <hip/hip_runtime.h>

typedef unsigned short u16;
typedef unsigned int u32;
typedef unsigned long long u64;

#define GN 100000
#define GE 1600000

// bucketed CSR build: 196 dst-ranges (512 nodes) x 8 XCD-local sub-buckets
#define NRANGE 196
#define NBKT   (NRANGE * 8)     // 1568
#define BCAP   1536             // mean fill ~1020, +16 sigma
#define OVFCAP 65536

typedef __bf16 bf16x8 __attribute__((ext_vector_type(8)));
typedef float f32x4 __attribute__((ext_vector_type(4)));

__device__ __forceinline__ float bl(u32 u){ return __uint_as_float(u << 16); }
__device__ __forceinline__ float bh(u32 u){ return __uint_as_float(u & 0xffff0000u); }
__device__ __forceinline__ float bfu(u16 v){ return __uint_as_float(((u32)v) << 16); }
__device__ __forceinline__ u16 f2bf(float f){
    u32 u = __float_as_uint(f);
    u32 r = (u + 0x7fffu + ((u >> 16) & 1u)) >> 16;
    return (u16)r;
}

// ---- init: zero deg/colsum/bcur/ovf; detect edge int32/int64; detect x f32/bf16 ----
// flags[0]: 1 => edge_index int64; flags[1]: 1 => float tensors are f32; flags[2]: ovf count
__global__ void __launch_bounds__(256) k_init(const int* ei, const u32* xraw,
                                              int* deg, float* colsum, int* flags, int* bcur){
    int i = blockIdx.x * 256 + threadIdx.x;
    if (i < GN) deg[i] = 0;
    if (i < NBKT) bcur[i] = 0;
    int t = threadIdx.x;
    if (blockIdx.x == 0){
        __shared__ int s_any[4];
        colsum[t] = 0.f;
        int v = 0;
        #pragma unroll
        for (int j = 0; j < 4; ++j){
            int k = t * 4 + j;                // k in [0,1024)
            v |= ei[2 * k * 1000 + 1];        // dword pos <= 2046001 < 3.2M
        }
        #pragma unroll
        for (int m = 1; m < 64; m <<= 1) v |= __shfl_xor(v, m);
        if ((t & 63) == 0) s_any[t >> 6] = v;
        __syncthreads();
        if (t == 0){
            int any = s_any[0] | s_any[1] | s_any[2] | s_any[3];
            flags[0] = (any == 0) ? 1 : 0;
            flags[2] = 0;                     // overflow counter
        }
    }
    if (blockIdx.x == 1){
        __shared__ int s_cnt[4];
        // low u16 of each dword: bf16 of ~N(0,1) has exponent in [100,140];
        // f32 mantissa bits hit that window ~16% of the time.
        int cnt = 0;
        #pragma unroll
        for (int j = 0; j < 4; ++j){
            int idx = (t * 4 + j) * 6000 + 3;     // < 6.15M dwords, safe both ways
            u32 u = xraw[idx];
            int e = (u >> 7) & 0xFF;
            cnt += (e >= 100 && e <= 140) ? 1 : 0;
        }
        #pragma unroll
        for (int m = 1; m < 64; m <<= 1) cnt += __shfl_xor(cnt, m);
        if ((t & 63) == 0) s_cnt[t >> 6] = cnt;
        __syncthreads();
        if (t == 0){
            int tot = s_cnt[0] + s_cnt[1] + s_cnt[2] + s_cnt[3];
            flags[1] = (tot > 512) ? 0 : 1;
        }
    }
}

// ---- convert x -> internal bf16 (copy if already bf16) ----
__global__ void __launch_bounds__(256) k_convx(const void* x, const int* flags, u16* xb){
    int gid = blockIdx.x * 256 + threadIdx.x;     // one 8-element chunk
    if (gid >= GN * 16) return;
    if (flags[1]){
        const uint4* xf = (const uint4*)x;
        uint4 a = xf[gid * 2], b = xf[gid * 2 + 1];
        u32 r0 = (u32)f2bf(__uint_as_float(a.x)) | ((u32)f2bf(__uint_as_float(a.y)) << 16);
        u32 r1 = (u32)f2bf(__uint_as_float(a.z)) | ((u32)f2bf(__uint_as_float(a.w)) << 16);
        u32 r2 = (u32)f2bf(__uint_as_float(b.x)) | ((u32)f2bf(__uint_as_float(b.y)) << 16);
        u32 r3 = (u32)f2bf(__uint_as_float(b.z)) | ((u32)f2bf(__uint_as_float(b.w)) << 16);
        uint4 o = {r0, r1, r2, r3};
        ((uint4*)xb)[gid] = o;
    } else {
        ((uint4*)xb)[gid] = ((const uint4*)x)[gid];
    }
}

// ---- convert all params -> contiguous bf16 block (+ f32 copy of biases) ----
// layout: Wl[49152] | Wr[49152] | b[384] | gamma[384] | beta[384]
//         | wlout[128] | wrout[128] | bout[1]
#define WOFF_WR    49152
#define WOFF_B     98304
#define WOFF_G     98688
#define WOFF_BE    99072
#define WOFF_WLO   99456
#define WOFF_WRO   99584
#define WOFF_BO    99712
#define WTOT       99713
__global__ void __launch_bounds__(256) k_convw(const void* Wl, const void* Wr, const void* b,
                                               const void* g, const void* be, const void* wlo,
                                               const void* wro, const void* bo,
                                               const int* flags, u16* wbuf, float* biasf){
    int i = blockIdx.x * 256 + threadIdx.x;
    if (i >= WTOT) return;
    const void* s; int k;
    if      (i < WOFF_WR ){ s = Wl;  k = i; }
    else if (i < WOFF_B  ){ s = Wr;  k = i - WOFF_WR; }
    else if (i < WOFF_G  ){ s = b;   k = i - WOFF_B; }
    else if (i < WOFF_BE ){ s = g;   k = i - WOFF_G; }
    else if (i < WOFF_WLO){ s = be;  k = i - WOFF_BE; }
    else if (i < WOFF_WRO){ s = wlo; k = i - WOFF_WLO; }
    else if (i < WOFF_BO ){ s = wro; k = i - WOFF_WRO; }
    else                  { s = bo;  k = 0; }
    float fv = flags[1] ? ((const float*)s)[k] : bfu(((const u16*)s)[k]);
    wbuf[i] = f2bf(fv);
    if (i >= WOFF_B && i < WOFF_B + 384) biasf[i - WOFF_B] = fv;
}

// ---- pass A: deg histogram + append (dst,src) pairs into XCD-local sub-buckets ----
__global__ void __launch_bounds__(256) k_bucket(const int* ei, const int* flags, int* deg,
                                                int* bcur, u64* pairs, u64* ovf, int* ovfcnt){
    int e = blockIdx.x * 256 + threadIdx.x;
    if (e >= GE) return;
    int s, d;
    if (flags[0]){ s = ei[2 * e]; d = ei[2 * (GE + e)]; }
    else         { s = ei[e];     d = ei[GE + e]; }
    atomicAdd(&deg[d], 1);
    int bkt = ((d >> 9) << 3) | (blockIdx.x & 7);   // dst-range x XCD residue
    int pos = atomicAdd(&bcur[bkt], 1);
    u64 pr = ((u64)(u32)d << 32) | (u32)s;
    if (pos < BCAP) pairs[(size_t)bkt * BCAP + pos] = pr;
    else {
        int op = atomicAdd(ovfcnt, 1);
        if (op < OVFCAP) ovf[op] = pr;
    }
}

// ---- 3-kernel exclusive scan of deg -> rowptr ----
__global__ void __launch_bounds__(256) k_scan1(const int* deg, int* rowptr, int* bsum){
    __shared__ int ls[256];
    int t = threadIdx.x, b = blockIdx.x;
    int base = b * 1024 + t * 4;
    int d0 = 0, d1 = 0, d2 = 0, d3 = 0;
    if (base + 3 < GN){
        int4 v = *(const int4*)(deg + base);
        d0 = v.x; d1 = v.y; d2 = v.z; d3 = v.w;
    } else {
        if (base     < GN) d0 = deg[base];
        if (base + 1 < GN) d1 = deg[base + 1];
        if (base + 2 < GN) d2 = deg[base + 2];
        if (base + 3 < GN) d3 = deg[base + 3];
    }
    int s = d0 + d1 + d2 + d3;
    ls[t] = s; __syncthreads();
    for (int off = 1; off < 256; off <<= 1){
        int v = (t >= off) ? ls[t - off] : 0;
        __syncthreads();
        ls[t] += v;
        __syncthreads();
    }
    int excl = ls[t] - s;
    if (t == 255) bsum[b] = ls[255];
    if (base     < GN) rowptr[base]     = excl;
    if (base + 1 < GN) rowptr[base + 1] = excl + d0;
    if (base + 2 < GN) rowptr[base + 2] = excl + d0 + d1;
    if (base + 3 < GN) rowptr[base + 3] = excl + d0 + d1 + d2;
}

__global__ void __launch_bounds__(128) k_scan2(const int* bsum, int* boff, int* rowptr){
    __shared__ int ls[128];
    int t = threadIdx.x;
    const int nb = (GN + 1023) / 1024;  // 98
    int v = (t < nb) ? bsum[t] : 0;
    ls[t] = v; __syncthreads();
    for (int off = 1; off < 128; off <<= 1){
        int u = (t >= off) ? ls[t - off] : 0;
        __syncthreads();
        ls[t] += u;
        __syncthreads();
    }
    if (t < nb) boff[t] = ls[t] - v;
    if (t == 0) rowptr[GN] = GE;
}

__global__ void __launch_bounds__(256) k_scan3(int* rowptr, int* cursor, const int* deg,
                                               const int* boff, float* invdeg){
    int i = blockIdx.x * 256 + threadIdx.x;
    if (i >= GN) return;
    int rp = rowptr[i] + boff[i >> 10];
    rowptr[i] = rp;
    cursor[i] = rp;
    int d = deg[i];
    invdeg[i] = (d > 0) ? 1.f / (float)d : 0.f;
}

// ---- pass B: one block per dst-range, scatter into L2-resident col window ----
__global__ void __launch_bounds__(256) k_place(const int* bcur, const u64* pairs,
                                               int* cursor, int* col){
    int range = blockIdx.x;
    #pragma unroll 1
    for (int sub = 0; sub < 8; ++sub){
        int b = range * 8 + sub;
        int cnt = bcur[b]; if (cnt > BCAP) cnt = BCAP;
        const u64* P = pairs + (size_t)b * BCAP;
        for (int i = threadIdx.x; i < cnt; i += 256){
            u64 pr = P[i];
            int s = (int)(u32)pr, d = (int)(pr >> 32);
            int pos = atomicAdd(&cursor[d], 1);
            col[pos] = s;
        }
    }
}

__global__ void __launch_bounds__(256) k_ovf(const int* ovfcnt, const u64* ovf,
                                             int* cursor, int* col){
    int total = *ovfcnt; if (total > OVFCAP) total = OVFCAP;
    for (int i = blockIdx.x * 256 + threadIdx.x; i < total; i += 32 * 256){
        u64 pr = ovf[i];
        int s = (int)(u32)pr, d = (int)(pr >> 32);
        int pos = atomicAdd(&cursor[d], 1);
        col[pos] = s;
    }
}

// ---- mean aggregation: one wave per node, 8 outstanding row-gathers ----
__global__ void __launch_bounds__(256) k_agg(const u16* hin, const int* rowptr, const int* col,
                                             const float* invdeg, u16* amean){
    int wid = threadIdx.x >> 6, lane = threadIdx.x & 63;
    int node = blockIdx.x * 4 + wid;
    if (node >= GN) return;
    int beg = rowptr[node], end = rowptr[node + 1];
    const u32* h32 = (const u32*)hin;
    float lo = 0.f, hi = 0.f;
    int e = beg;
    for (; e + 7 < end; e += 8){
        u32 v0 = h32[col[e]     * 64 + lane];
        u32 v1 = h32[col[e + 1] * 64 + lane];
        u32 v2 = h32[col[e + 2] * 64 + lane];
        u32 v3 = h32[col[e + 3] * 64 + lane];
        u32 v4 = h32[col[e + 4] * 64 + lane];
        u32 v5 = h32[col[e + 5] * 64 + lane];
        u32 v6 = h32[col[e + 6] * 64 + lane];
        u32 v7 = h32[col[e + 7] * 64 + lane];
        lo += bl(v0) + bl(v1) + bl(v2) + bl(v3) + bl(v4) + bl(v5) + bl(v6) + bl(v7);
        hi += bh(v0) + bh(v1) + bh(v2) + bh(v3) + bh(v4) + bh(v5) + bh(v6) + bh(v7);
    }
    for (; e + 3 < end; e += 4){
        u32 v0 = h32[col[e]     * 64 + lane];
        u32 v1 = h32[col[e + 1] * 64 + lane];
        u32 v2 = h32[col[e + 2] * 64 + lane];
        u32 v3 = h32[col[e + 3] * 64 + lane];
        lo += bl(v0) + bl(v1) + bl(v2) + bl(v3);
        hi += bh(v0) + bh(v1) + bh(v2) + bh(v3);
    }
    for (; e < end; ++e){
        u32 v = h32[col[e] * 64 + lane];
        lo += bl(v); hi += bh(v);
    }
    float inv = invdeg[node];
    lo *= inv; hi *= inv;
    u32 packed = (u32)f2bf(lo) | ((u32)f2bf(hi) << 16);
    ((u32*)amean)[node * 64 + lane] = packed;
}

// ---- fused GEMM: hout = relu([amean|hin] @ [Wl;Wr] + b), + BN column stats ----
__global__ void __launch_bounds__(256) k_gemm(const u16* amean, const u16* hin,
                                              const u16* Wl, const u16* Wr, const float* biasf,
                                              u16* hout, float* colsum){
    __shared__ __align__(16) u16 wlds[32768];  // [kc=32][c=128][8] bf16, 64KB
    int t = threadIdx.x;
    for (int idx = t; idx < 16384; idx += 256){
        int k = idx >> 7, c = idx & 127;
        wlds[((k >> 3) << 10) + (c << 3) + (k & 7)] = Wl[idx];
        int k2 = k + 128;
        wlds[((k2 >> 3) << 10) + (c << 3) + (k2 & 7)] = Wr[idx];
    }
    __syncthreads();
    int wid = t >> 6, lane = t & 63;
    int quad = lane >> 4, l15 = lane & 15;
    int r0 = blockIdx.x * 128 + wid * 32;
    int rowa = r0 + l15, rowb = rowa + 16;
    f32x4 acc[2][8];
    #pragma unroll
    for (int i = 0; i < 2; i++)
        #pragma unroll
        for (int j = 0; j < 8; j++) acc[i][j] = (f32x4){0.f, 0.f, 0.f, 0.f};

    #pragma unroll
    for (int s = 0; s < 8; ++s){
        const u16* A = (s < 4) ? amean : hin;
        int kk = ((s & 3) << 5) + (quad << 3);
        union { uint4 u; bf16x8 v; } fa0, fa1;
        fa0.u = (rowa < GN) ? *(const uint4*)(A + rowa * 128 + kk) : make_uint4(0,0,0,0);
        fa1.u = (rowb < GN) ? *(const uint4*)(A + rowb * 128 + kk) : make_uint4(0,0,0,0);
        int kc = (s << 2) + quad;
        const u16* wb = &wlds[(kc << 10) + (l15 << 3)];
        #pragma unroll
        for (int cb = 0; cb < 8; ++cb){
            union { uint4 u; bf16x8 v; } fb;
            fb.u = *(const uint4*)(wb + (cb << 7));
            acc[0][cb] = __builtin_amdgcn_mfma_f32_16x16x32_bf16(fa0.v, fb.v, acc[0][cb], 0, 0, 0);
            acc[1][cb] = __builtin_amdgcn_mfma_f32_16x16x32_bf16(fa1.v, fb.v, acc[1][cb], 0, 0, 0);
        }
    }
    __syncthreads();                  // done reading wlds; reuse for stats
    float* sst = (float*)wlds;        // [256]: sum[128], sumsq[128]
    sst[t] = 0.f;
    __syncthreads();

    float bsv[8];
    #pragma unroll
    for (int cb = 0; cb < 8; cb++) bsv[cb] = biasf[cb * 16 + l15];

    #pragma unroll
    for (int cb = 0; cb < 8; cb++){
        float csum = 0.f, csq = 0.f;
        #pragma unroll
        for (int rb = 0; rb < 2; rb++){
            int rbase = r0 + rb * 16 + quad * 4;
            #pragma unroll
            for (int rr = 0; rr < 4; rr++){
                int row = rbase + rr;
                float v = acc[rb][cb][rr] + bsv[cb];
                v = fmaxf(v, 0.f);
                if (row < GN) hout[row * 128 + cb * 16 + l15] = f2bf(v);
                float vm = (row < GN) ? v : 0.f;
                csum += vm; csq += vm * vm;
            }
        }
        csum += __shfl_xor(csum, 16); csum += __shfl_xor(csum, 32);
        csq  += __shfl_xor(csq, 16);  csq  += __shfl_xor(csq, 32);
        if (quad == 0){
            atomicAdd(&sst[cb * 16 + l15], csum);
            atomicAdd(&sst[128 + cb * 16 + l15], csq);
        }
    }
    __syncthreads();
    atomicAdd(&colsum[t], sst[t]);
}

// ---- BN finalize: per-column scale/shift; re-zero colsum for next layer ----
__global__ void __launch_bounds__(256) k_bn(float* colsum, const u16* gamma, const u16* beta, float* scsh){
    int t = threadIdx.x;
    float s = 0.f, q = 0.f;
    if (t < 128){ s = colsum[t]; q = colsum[128 + t]; }
    __syncthreads();
    colsum[t] = 0.f;
    if (t < 128){
        const float invn = 1.f / (float)GN;
        float mean = s * invn;
        float var = fmaxf(q * invn - mean * mean, 0.f);
        float rstd = rsqrtf(var + 1e-5f);
        float g  = bfu(gamma[t]);
        float be = bfu(beta[t]);
        float sc = g * rstd;
        scsh[t] = sc;
        scsh[128 + t] = be - mean * sc;
    }
}

// ---- fold BN affine into next layer's weights: W' = diag(sc)W, b' = b + sh@(Wl+Wr) ----
__global__ void __launch_bounds__(256) k_fold(const float* scsh, const u16* Wls, const u16* Wrs,
                                              const float* bsrc, u16* wfd, float* bfd){
    int b = blockIdx.x, t = threadIdx.x;
    if (b < 64){
        int idx = b * 256 + t;            // 0..16383
        int k = idx >> 7;
        float sc = scsh[k];
        wfd[idx]         = f2bf(sc * bfu(Wls[idx]));
        wfd[16384 + idx] = f2bf(sc * bfu(Wrs[idx]));
    } else if (t < 128){
        float acc = bsrc[t];
        for (int k = 0; k < 128; ++k){
            float sh = scsh[128 + k];
            acc += sh * (bfu(Wls[k * 128 + t]) + bfu(Wrs[k * 128 + t]));
        }
        bfd[t] = acc;
    }
}

// ---- fold BN affine into the output head ----
__global__ void __launch_bounds__(64) k_hfold(const float* scsh, const u16* wlo, const u16* wro,
                                              const u16* bo, u16* hwl, u16* hwr, float* hb){
    int l = threadIdx.x;
    float contrib = 0.f;
    #pragma unroll
    for (int j = 0; j < 2; ++j){
        int t = l + j * 64;
        float sc = scsh[t], sh = scsh[128 + t];
        float wl = bfu(wlo[t]), wr = bfu(wro[t]);
        hwl[t] = f2bf(sc * wl);
        hwr[t] = f2bf(sc * wr);
        contrib += sh * (wl + wr);
    }
    #pragma unroll
    for (int m = 1; m < 64; m <<= 1) contrib += __shfl_xor(contrib, m);
    if (l == 0) hb[0] = contrib + bfu(bo[0]);
}

// ---- output head: y = h@Wl', r = h@Wr' (wave per node) ----
__global__ void __launch_bounds__(256) k_dot(const u16* h, const u16* wl, const u16* wr,
                                             float* y, float* r){
    int node = (blockIdx.x * 256 + threadIdx.x) >> 6;
    int lane = threadIdx.x & 63;
    if (node >= GN) return;
    u32 hv  = ((const u32*)h)[node * 64 + lane];
    u32 wlv = ((const u32*)wl)[lane];
    u32 wrv = ((const u32*)wr)[lane];
    float hlo = bl(hv), hhi = bh(hv);
    float ya = hlo * bl(wlv) + hhi * bh(wlv);
    float ra = hlo * bl(wrv) + hhi * bh(wrv);
    #pragma unroll
    for (int m = 1; m < 64; m <<= 1){ ya += __shfl_xor(ya, m); ra += __shfl_xor(ra, m); }
    if (lane == 0){ y[node] = ya; r[node] = ra; }
}

__global__ void __launch_bounds__(256) k_out(const float* y, const float* r, const int* rowptr,
                                             const int* col, const float* invdeg, const float* hb,
                                             const int* flags, void* out){
    int n = blockIdx.x * 256 + threadIdx.x;
    if (n >= GN) return;
    int beg = rowptr[n], end = rowptr[n + 1];
    float s = 0.f;
    for (int e = beg; e < end; ++e) s += y[col[e]];
    float z = invdeg[n] * s + r[n] + hb[0];
    float sg = 1.f / (1.f + __expf(-z));
    if (flags[1]) ((float*)out)[n] = sg;
    else          ((u16*)out)[n] = f2bf(sg);
}

extern "C" void kernel_launch(void* const* d_in, const int* in_sizes, int n_in,
                              void* d_out, int out_size, void* d_ws, size_t ws_size,
                              hipStream_t stream) {
    const void* x     = d_in[0];
    const int*  ei    = (const int*)d_in[1];
    const void* Wl    = d_in[2];
    const void* Wr    = d_in[3];
    const void* bias  = d_in[4];
    const void* gamma = d_in[5];
    const void* beta  = d_in[6];
    const void* wlout = d_in[7];
    const void* wrout = d_in[8];
    const void* bout  = d_in[9];

    char* p = (char*)d_ws;
    auto take = [&](size_t b){ void* q = (void*)p; p += (b + 255) & ~(size_t)255; return q; };
    int*   deg    = (int*)  take((size_t)GN * 4);
    int*   rowptr = (int*)  take((size_t)(GN + 1) * 4);
    int*   cursor = (int*)  take((size_t)GN * 4);
    int*   bsum   = (int*)  take(512);
    int*   boff   = (int*)  take(512);
    int*   flags  = (int*)  take(256);
    int*   bcur   = (int*)  take((size_t)NBKT * 4);
    float* invdeg = (float*)take((size_t)GN * 4);
    float* colsum = (float*)take(256 * 4);
    float* scsh   = (float*)take(256 * 4);
    float* biasf  = (float*)take(384 * 4);
    float* bf2    = (float*)take(128 * 4);
    float* bf3    = (float*)take(128 * 4);
    float* hb     = (float*)take(256);
    u16*   wf2    = (u16*)  take(32768 * 2);
    u16*   wf3    = (u16*)  take(32768 * 2);
    u16*   hwl    = (u16*)  take(128 * 2);
    u16*   hwr    = (u16*)  take(128 * 2);
    float* yv     = (float*)take((size_t)GN * 4);
    float* rv     = (float*)take((size_t)GN * 4);
    int*   col    = (int*)  take((size_t)GE * 4);
    u16*   xb     = (u16*)  take((size_t)GN * 128 * 2);
    u16*   amean  = (u16*)  take((size_t)GN * 128 * 2);
    u16*   hbuf   = (u16*)  take((size_t)GN * 128 * 2);
    u16*   wbuf   = (u16*)  take((size_t)WTOT * 2);

    // overlays: pairs lives in amean (19.3MB <= 25.6MB), ovf in hbuf; both
    // are dead before the first k_agg/k_gemm writes them.
    u64* pairs = (u64*)amean;
    u64* ovf   = (u64*)hbuf;
    int* ovfcnt = flags + 2;

    const int NB_N = (GN + 255) / 256;          // 391
    const int NB_E = (GE + 255) / 256;          // 6250
    const int NB_S = (GN + 1023) / 1024;        // 98
    const int NB_W = (GN + 3) / 4;              // 25000 (wave per node)
    const int NB_G = (GN + 127) / 128;          // 782
    const int NB_M = (GN * 16 + 255) / 256;     // 6250
    const int NB_C = (WTOT + 255) / 256;        // 390

    k_init  <<<NB_N, 256, 0, stream>>>(ei, (const u32*)x, deg, colsum, flags, bcur);
    k_convx <<<NB_M, 256, 0, stream>>>(x, flags, xb);
    k_convw <<<NB_C, 256, 0, stream>>>(Wl, Wr, bias, gamma, beta, wlout, wrout, bout, flags, wbuf, biasf);
    k_bucket<<<NB_E, 256, 0, stream>>>(ei, flags, deg, bcur, pairs, ovf, ovfcnt);
    k_scan1 <<<NB_S, 256, 0, stream>>>(deg, rowptr, bsum);
    k_scan2 <<<1,    128, 0, stream>>>(bsum, boff, rowptr);
    k_scan3 <<<NB_N, 256, 0, stream>>>(rowptr, cursor, deg, boff, invdeg);
    k_place <<<NRANGE, 256, 0, stream>>>(bcur, pairs, cursor, col);
    k_ovf   <<<32,   256, 0, stream>>>(ovfcnt, ovf, cursor, col);

    const u16* hin = xb;
    for (int i = 0; i < 3; ++i){
        const u16* Wli; const u16* Wri; const float* bfi;
        if (i == 0){ Wli = wbuf;              Wri = wbuf + WOFF_WR;          bfi = biasf; }
        else if (i == 1){ Wli = wf2;          Wri = wf2 + 16384;             bfi = bf2; }
        else { Wli = wf3;                     Wri = wf3 + 16384;             bfi = bf3; }
        k_agg <<<NB_W, 256, 0, stream>>>(hin, rowptr, col, invdeg, amean);
        k_gemm<<<NB_G, 256, 0, stream>>>(amean, hin, Wli, Wri, bfi, hbuf, colsum);
        k_bn  <<<1,    256, 0, stream>>>(colsum, wbuf + WOFF_G + i * 128, wbuf + WOFF_BE + i * 128, scsh);
        if (i == 0)
            k_fold<<<65, 256, 0, stream>>>(scsh, wbuf + 16384, wbuf + WOFF_WR + 16384, biasf + 128, wf2, bf2);
        else if (i == 1)
            k_fold<<<65, 256, 0, stream>>>(scsh, wbuf + 32768, wbuf + WOFF_WR + 32768, biasf + 256, wf3, bf3);
        else
            k_hfold<<<1, 64, 0, stream>>>(scsh, wbuf + WOFF_WLO, wbuf + WOFF_WRO, wbuf + WOFF_BO, hwl, hwr, hb);
        hin = hbuf;
    }
    k_dot<<<NB_W, 256, 0, stream>>>(hbuf, hwl, hwr, yv, rv);
    k_out<<<NB_N, 256, 0, stream>>>(yv, rv, rowptr, col, invdeg, hb, flags, d_out);
}

// Round 4
// 683.497 us; speedup vs baseline: 1.3508x; 1.3508x over previous
//
#include <hip/hip_runtime.h>

typedef unsigned short u16;
typedef unsigned int u32;
typedef unsigned long long u64;

#define GN 100000
#define GE 1600000

typedef __bf16 bf16x8 __attribute__((ext_vector_type(8)));
typedef float f32x4 __attribute__((ext_vector_type(4)));

__device__ __forceinline__ float bl(u32 u){ return __uint_as_float(u << 16); }
__device__ __forceinline__ float bh(u32 u){ return __uint_as_float(u & 0xffff0000u); }
__device__ __forceinline__ float bfu(u16 v){ return __uint_as_float(((u32)v) << 16); }
__device__ __forceinline__ u16 f2bf(float f){
    u32 u = __float_as_uint(f);
    u32 r = (u + 0x7fffu + ((u >> 16) & 1u)) >> 16;
    return (u16)r;
}

// ---- init: zero deg/colsum; detect edge int32/int64; detect x f32/bf16 ----
// flags[0]: 1 => edge_index int64; flags[1]: 1 => float tensors are f32
__global__ void __launch_bounds__(256) k_init(const int* ei, const u32* xraw,
                                              int* deg, float* colsum, int* flags){
    int i = blockIdx.x * 256 + threadIdx.x;
    if (i < GN) deg[i] = 0;
    int t = threadIdx.x;
    if (blockIdx.x == 0){
        __shared__ int s_any[4];
        colsum[t] = 0.f;
        int v = 0;
        #pragma unroll
        for (int j = 0; j < 4; ++j){
            int k = t * 4 + j;                // k in [0,1024)
            v |= ei[2 * k * 1000 + 1];        // dword pos <= 2046001 < 3.2M
        }
        #pragma unroll
        for (int m = 1; m < 64; m <<= 1) v |= __shfl_xor(v, m);
        if ((t & 63) == 0) s_any[t >> 6] = v;
        __syncthreads();
        if (t == 0){
            int any = s_any[0] | s_any[1] | s_any[2] | s_any[3];
            flags[0] = (any == 0) ? 1 : 0;
        }
    }
    if (blockIdx.x == 1){
        __shared__ int s_cnt[4];
        // low u16 of each dword: bf16 of ~N(0,1) has exponent in [100,140];
        // f32 mantissa bits hit that window ~16% of the time.
        int cnt = 0;
        #pragma unroll
        for (int j = 0; j < 4; ++j){
            int idx = (t * 4 + j) * 6000 + 3;     // < 6.15M dwords, safe both ways
            u32 u = xraw[idx];
            int e = (u >> 7) & 0xFF;
            cnt += (e >= 100 && e <= 140) ? 1 : 0;
        }
        #pragma unroll
        for (int m = 1; m < 64; m <<= 1) cnt += __shfl_xor(cnt, m);
        if ((t & 63) == 0) s_cnt[t >> 6] = cnt;
        __syncthreads();
        if (t == 0){
            int tot = s_cnt[0] + s_cnt[1] + s_cnt[2] + s_cnt[3];
            flags[1] = (tot > 512) ? 0 : 1;
        }
    }
}

// ---- convert x -> internal bf16 (copy if already bf16) ----
__global__ void __launch_bounds__(256) k_convx(const void* x, const int* flags, u16* xb){
    int gid = blockIdx.x * 256 + threadIdx.x;     // one 8-element chunk
    if (gid >= GN * 16) return;
    if (flags[1]){
        const uint4* xf = (const uint4*)x;
        uint4 a = xf[gid * 2], b = xf[gid * 2 + 1];
        u32 r0 = (u32)f2bf(__uint_as_float(a.x)) | ((u32)f2bf(__uint_as_float(a.y)) << 16);
        u32 r1 = (u32)f2bf(__uint_as_float(a.z)) | ((u32)f2bf(__uint_as_float(a.w)) << 16);
        u32 r2 = (u32)f2bf(__uint_as_float(b.x)) | ((u32)f2bf(__uint_as_float(b.y)) << 16);
        u32 r3 = (u32)f2bf(__uint_as_float(b.z)) | ((u32)f2bf(__uint_as_float(b.w)) << 16);
        uint4 o = {r0, r1, r2, r3};
        ((uint4*)xb)[gid] = o;
    } else {
        ((uint4*)xb)[gid] = ((const uint4*)x)[gid];
    }
}

// ---- convert all params -> contiguous bf16 block (+ f32 copy of biases) ----
// layout: Wl[49152] | Wr[49152] | b[384] | gamma[384] | beta[384]
//         | wlout[128] | wrout[128] | bout[1]
#define WOFF_WR    49152
#define WOFF_B     98304
#define WOFF_G     98688
#define WOFF_BE    99072
#define WOFF_WLO   99456
#define WOFF_WRO   99584
#define WOFF_BO    99712
#define WTOT       99713
__global__ void __launch_bounds__(256) k_convw(const void* Wl, const void* Wr, const void* b,
                                               const void* g, const void* be, const void* wlo,
                                               const void* wro, const void* bo,
                                               const int* flags, u16* wbuf, float* biasf){
    int i = blockIdx.x * 256 + threadIdx.x;
    if (i >= WTOT) return;
    const void* s; int k;
    if      (i < WOFF_WR ){ s = Wl;  k = i; }
    else if (i < WOFF_B  ){ s = Wr;  k = i - WOFF_WR; }
    else if (i < WOFF_G  ){ s = b;   k = i - WOFF_B; }
    else if (i < WOFF_BE ){ s = g;   k = i - WOFF_G; }
    else if (i < WOFF_WLO){ s = be;  k = i - WOFF_BE; }
    else if (i < WOFF_WRO){ s = wlo; k = i - WOFF_WLO; }
    else if (i < WOFF_BO ){ s = wro; k = i - WOFF_WRO; }
    else                  { s = bo;  k = 0; }
    float fv = flags[1] ? ((const float*)s)[k] : bfu(((const u16*)s)[k]);
    wbuf[i] = f2bf(fv);
    if (i >= WOFF_B && i < WOFF_B + 384) biasf[i - WOFF_B] = fv;
}

// ---- XCD-sharded degree count: block b handles edge chunk b>>3, commits only
// dsts whose 512-node range has residue b&7. Under round-robin block->XCD
// dispatch, all atomics/lines of one range come from one XCD.
__global__ void __launch_bounds__(256) k_count_sh(const int* ei, const int* flags, int* deg){
    int res = blockIdx.x & 7;
    int base = (blockIdx.x >> 3) * 1024;
    int is64 = flags[0];
    #pragma unroll
    for (int k = 0; k < 4; ++k){
        int e = base + k * 256 + threadIdx.x;
        if (e >= GE) continue;
        int d = is64 ? ei[2 * (GE + e)] : ei[GE + e];
        if (((d >> 9) & 7) == res) atomicAdd(&deg[d], 1);
    }
}

// ---- 3-kernel exclusive scan of deg -> rowptr ----
__global__ void __launch_bounds__(256) k_scan1(const int* deg, int* rowptr, int* bsum){
    __shared__ int ls[256];
    int t = threadIdx.x, b = blockIdx.x;
    int base = b * 1024 + t * 4;
    int d0 = 0, d1 = 0, d2 = 0, d3 = 0;
    if (base + 3 < GN){
        int4 v = *(const int4*)(deg + base);
        d0 = v.x; d1 = v.y; d2 = v.z; d3 = v.w;
    } else {
        if (base     < GN) d0 = deg[base];
        if (base + 1 < GN) d1 = deg[base + 1];
        if (base + 2 < GN) d2 = deg[base + 2];
        if (base + 3 < GN) d3 = deg[base + 3];
    }
    int s = d0 + d1 + d2 + d3;
    ls[t] = s; __syncthreads();
    for (int off = 1; off < 256; off <<= 1){
        int v = (t >= off) ? ls[t - off] : 0;
        __syncthreads();
        ls[t] += v;
        __syncthreads();
    }
    int excl = ls[t] - s;
    if (t == 255) bsum[b] = ls[255];
    if (base     < GN) rowptr[base]     = excl;
    if (base + 1 < GN) rowptr[base + 1] = excl + d0;
    if (base + 2 < GN) rowptr[base + 2] = excl + d0 + d1;
    if (base + 3 < GN) rowptr[base + 3] = excl + d0 + d1 + d2;
}

__global__ void __launch_bounds__(128) k_scan2(const int* bsum, int* boff, int* rowptr){
    __shared__ int ls[128];
    int t = threadIdx.x;
    const int nb = (GN + 1023) / 1024;  // 98
    int v = (t < nb) ? bsum[t] : 0;
    ls[t] = v; __syncthreads();
    for (int off = 1; off < 128; off <<= 1){
        int u = (t >= off) ? ls[t - off] : 0;
        __syncthreads();
        ls[t] += u;
        __syncthreads();
    }
    if (t < nb) boff[t] = ls[t] - v;
    if (t == 0) rowptr[GN] = GE;
}

__global__ void __launch_bounds__(256) k_scan3(int* rowptr, int* cursor, const int* deg,
                                               const int* boff, float* invdeg){
    int i = blockIdx.x * 256 + threadIdx.x;
    if (i >= GN) return;
    int rp = rowptr[i] + boff[i >> 10];
    rowptr[i] = rp;
    cursor[i] = rp;
    int d = deg[i];
    invdeg[i] = (d > 0) ? 1.f / (float)d : 0.f;
}

// ---- XCD-sharded CSR fill: same residue filter as k_count_sh, so each
// range's col window + cursor lines are written from a single XCD.
__global__ void __launch_bounds__(256) k_fill_sh(const int* ei, const int* flags,
                                                 int* cursor, int* col){
    int res = blockIdx.x & 7;
    int base = (blockIdx.x >> 3) * 1024;
    int is64 = flags[0];
    #pragma unroll
    for (int k = 0; k < 4; ++k){
        int e = base + k * 256 + threadIdx.x;
        if (e >= GE) continue;
        int s, d;
        if (is64){ d = ei[2 * (GE + e)]; s = ei[2 * e]; }
        else     { d = ei[GE + e];       s = ei[e]; }
        if (((d >> 9) & 7) == res){
            int pos = atomicAdd(&cursor[d], 1);
            col[pos] = s;
        }
    }
}

// ---- mean aggregation: one wave per node, 8 outstanding row-gathers ----
__global__ void __launch_bounds__(256) k_agg(const u16* hin, const int* rowptr, const int* col,
                                             const float* invdeg, u16* amean){
    int wid = threadIdx.x >> 6, lane = threadIdx.x & 63;
    int node = blockIdx.x * 4 + wid;
    if (node >= GN) return;
    int beg = rowptr[node], end = rowptr[node + 1];
    const u32* h32 = (const u32*)hin;
    float lo = 0.f, hi = 0.f;
    int e = beg;
    for (; e + 7 < end; e += 8){
        u32 v0 = h32[col[e]     * 64 + lane];
        u32 v1 = h32[col[e + 1] * 64 + lane];
        u32 v2 = h32[col[e + 2] * 64 + lane];
        u32 v3 = h32[col[e + 3] * 64 + lane];
        u32 v4 = h32[col[e + 4] * 64 + lane];
        u32 v5 = h32[col[e + 5] * 64 + lane];
        u32 v6 = h32[col[e + 6] * 64 + lane];
        u32 v7 = h32[col[e + 7] * 64 + lane];
        lo += bl(v0) + bl(v1) + bl(v2) + bl(v3) + bl(v4) + bl(v5) + bl(v6) + bl(v7);
        hi += bh(v0) + bh(v1) + bh(v2) + bh(v3) + bh(v4) + bh(v5) + bh(v6) + bh(v7);
    }
    for (; e + 3 < end; e += 4){
        u32 v0 = h32[col[e]     * 64 + lane];
        u32 v1 = h32[col[e + 1] * 64 + lane];
        u32 v2 = h32[col[e + 2] * 64 + lane];
        u32 v3 = h32[col[e + 3] * 64 + lane];
        lo += bl(v0) + bl(v1) + bl(v2) + bl(v3);
        hi += bh(v0) + bh(v1) + bh(v2) + bh(v3);
    }
    for (; e < end; ++e){
        u32 v = h32[col[e] * 64 + lane];
        lo += bl(v); hi += bh(v);
    }
    float inv = invdeg[node];
    lo *= inv; hi *= inv;
    u32 packed = (u32)f2bf(lo) | ((u32)f2bf(hi) << 16);
    ((u32*)amean)[node * 64 + lane] = packed;
}

// ---- fused GEMM: hout = relu([amean|hin] @ [Wl;Wr] + b), + BN column stats ----
__global__ void __launch_bounds__(256) k_gemm(const u16* amean, const u16* hin,
                                              const u16* Wl, const u16* Wr, const float* biasf,
                                              u16* hout, float* colsum){
    __shared__ __align__(16) u16 wlds[32768];  // [kc=32][c=128][8] bf16, 64KB
    int t = threadIdx.x;
    for (int idx = t; idx < 16384; idx += 256){
        int k = idx >> 7, c = idx & 127;
        wlds[((k >> 3) << 10) + (c << 3) + (k & 7)] = Wl[idx];
        int k2 = k + 128;
        wlds[((k2 >> 3) << 10) + (c << 3) + (k2 & 7)] = Wr[idx];
    }
    __syncthreads();
    int wid = t >> 6, lane = t & 63;
    int quad = lane >> 4, l15 = lane & 15;
    int r0 = blockIdx.x * 128 + wid * 32;
    int rowa = r0 + l15, rowb = rowa + 16;
    f32x4 acc[2][8];
    #pragma unroll
    for (int i = 0; i < 2; i++)
        #pragma unroll
        for (int j = 0; j < 8; j++) acc[i][j] = (f32x4){0.f, 0.f, 0.f, 0.f};

    #pragma unroll
    for (int s = 0; s < 8; ++s){
        const u16* A = (s < 4) ? amean : hin;
        int kk = ((s & 3) << 5) + (quad << 3);
        union { uint4 u; bf16x8 v; } fa0, fa1;
        fa0.u = (rowa < GN) ? *(const uint4*)(A + rowa * 128 + kk) : make_uint4(0,0,0,0);
        fa1.u = (rowb < GN) ? *(const uint4*)(A + rowb * 128 + kk) : make_uint4(0,0,0,0);
        int kc = (s << 2) + quad;
        const u16* wb = &wlds[(kc << 10) + (l15 << 3)];
        #pragma unroll
        for (int cb = 0; cb < 8; ++cb){
            union { uint4 u; bf16x8 v; } fb;
            fb.u = *(const uint4*)(wb + (cb << 7));
            acc[0][cb] = __builtin_amdgcn_mfma_f32_16x16x32_bf16(fa0.v, fb.v, acc[0][cb], 0, 0, 0);
            acc[1][cb] = __builtin_amdgcn_mfma_f32_16x16x32_bf16(fa1.v, fb.v, acc[1][cb], 0, 0, 0);
        }
    }
    __syncthreads();                  // done reading wlds; reuse for stats
    float* sst = (float*)wlds;        // [256]: sum[128], sumsq[128]
    sst[t] = 0.f;
    __syncthreads();

    float bsv[8];
    #pragma unroll
    for (int cb = 0; cb < 8; cb++) bsv[cb] = biasf[cb * 16 + l15];

    #pragma unroll
    for (int cb = 0; cb < 8; cb++){
        float csum = 0.f, csq = 0.f;
        #pragma unroll
        for (int rb = 0; rb < 2; rb++){
            int rbase = r0 + rb * 16 + quad * 4;
            #pragma unroll
            for (int rr = 0; rr < 4; rr++){
                int row = rbase + rr;
                float v = acc[rb][cb][rr] + bsv[cb];
                v = fmaxf(v, 0.f);
                if (row < GN) hout[row * 128 + cb * 16 + l15] = f2bf(v);
                float vm = (row < GN) ? v : 0.f;
                csum += vm; csq += vm * vm;
            }
        }
        csum += __shfl_xor(csum, 16); csum += __shfl_xor(csum, 32);
        csq  += __shfl_xor(csq, 16);  csq  += __shfl_xor(csq, 32);
        if (quad == 0){
            atomicAdd(&sst[cb * 16 + l15], csum);
            atomicAdd(&sst[128 + cb * 16 + l15], csq);
        }
    }
    __syncthreads();
    atomicAdd(&colsum[t], sst[t]);
}

// ---- BN finalize: per-column scale/shift; re-zero colsum for next layer ----
__global__ void __launch_bounds__(256) k_bn(float* colsum, const u16* gamma, const u16* beta, float* scsh){
    int t = threadIdx.x;
    float s = 0.f, q = 0.f;
    if (t < 128){ s = colsum[t]; q = colsum[128 + t]; }
    __syncthreads();
    colsum[t] = 0.f;
    if (t < 128){
        const float invn = 1.f / (float)GN;
        float mean = s * invn;
        float var = fmaxf(q * invn - mean * mean, 0.f);
        float rstd = rsqrtf(var + 1e-5f);
        float g  = bfu(gamma[t]);
        float be = bfu(beta[t]);
        float sc = g * rstd;
        scsh[t] = sc;
        scsh[128 + t] = be - mean * sc;
    }
}

// ---- fold BN affine into next layer's weights: W' = diag(sc)W, b' = b + sh@(Wl+Wr) ----
__global__ void __launch_bounds__(256) k_fold(const float* scsh, const u16* Wls, const u16* Wrs,
                                              const float* bsrc, u16* wfd, float* bfd){
    int b = blockIdx.x, t = threadIdx.x;
    if (b < 64){
        int idx = b * 256 + t;            // 0..16383
        int k = idx >> 7;
        float sc = scsh[k];
        wfd[idx]         = f2bf(sc * bfu(Wls[idx]));
        wfd[16384 + idx] = f2bf(sc * bfu(Wrs[idx]));
    } else if (t < 128){
        float acc = bsrc[t];
        for (int k = 0; k < 128; ++k){
            float sh = scsh[128 + k];
            acc += sh * (bfu(Wls[k * 128 + t]) + bfu(Wrs[k * 128 + t]));
        }
        bfd[t] = acc;
    }
}

// ---- fold BN affine into the output head ----
__global__ void __launch_bounds__(64) k_hfold(const float* scsh, const u16* wlo, const u16* wro,
                                              const u16* bo, u16* hwl, u16* hwr, float* hb){
    int l = threadIdx.x;
    float contrib = 0.f;
    #pragma unroll
    for (int j = 0; j < 2; ++j){
        int t = l + j * 64;
        float sc = scsh[t], sh = scsh[128 + t];
        float wl = bfu(wlo[t]), wr = bfu(wro[t]);
        hwl[t] = f2bf(sc * wl);
        hwr[t] = f2bf(sc * wr);
        contrib += sh * (wl + wr);
    }
    #pragma unroll
    for (int m = 1; m < 64; m <<= 1) contrib += __shfl_xor(contrib, m);
    if (l == 0) hb[0] = contrib + bfu(bo[0]);
}

// ---- output head: y = h@Wl', r = h@Wr' (wave per node) ----
__global__ void __launch_bounds__(256) k_dot(const u16* h, const u16* wl, const u16* wr,
                                             float* y, float* r){
    int node = (blockIdx.x * 256 + threadIdx.x) >> 6;
    int lane = threadIdx.x & 63;
    if (node >= GN) return;
    u32 hv  = ((const u32*)h)[node * 64 + lane];
    u32 wlv = ((const u32*)wl)[lane];
    u32 wrv = ((const u32*)wr)[lane];
    float hlo = bl(hv), hhi = bh(hv);
    float ya = hlo * bl(wlv) + hhi * bh(wlv);
    float ra = hlo * bl(wrv) + hhi * bh(wrv);
    #pragma unroll
    for (int m = 1; m < 64; m <<= 1){ ya += __shfl_xor(ya, m); ra += __shfl_xor(ra, m); }
    if (lane == 0){ y[node] = ya; r[node] = ra; }
}

__global__ void __launch_bounds__(256) k_out(const float* y, const float* r, const int* rowptr,
                                             const int* col, const float* invdeg, const float* hb,
                                             const int* flags, void* out){
    int n = blockIdx.x * 256 + threadIdx.x;
    if (n >= GN) return;
    int beg = rowptr[n], end = rowptr[n + 1];
    float s = 0.f;
    for (int e = beg; e < end; ++e) s += y[col[e]];
    float z = invdeg[n] * s + r[n] + hb[0];
    float sg = 1.f / (1.f + __expf(-z));
    if (flags[1]) ((float*)out)[n] = sg;
    else          ((u16*)out)[n] = f2bf(sg);
}

extern "C" void kernel_launch(void* const* d_in, const int* in_sizes, int n_in,
                              void* d_out, int out_size, void* d_ws, size_t ws_size,
                              hipStream_t stream) {
    const void* x     = d_in[0];
    const int*  ei    = (const int*)d_in[1];
    const void* Wl    = d_in[2];
    const void* Wr    = d_in[3];
    const void* bias  = d_in[4];
    const void* gamma = d_in[5];
    const void* beta  = d_in[6];
    const void* wlout = d_in[7];
    const void* wrout = d_in[8];
    const void* bout  = d_in[9];

    char* p = (char*)d_ws;
    auto take = [&](size_t b){ void* q = (void*)p; p += (b + 255) & ~(size_t)255; return q; };
    int*   deg    = (int*)  take((size_t)GN * 4);
    int*   rowptr = (int*)  take((size_t)(GN + 1) * 4);
    int*   cursor = (int*)  take((size_t)GN * 4);
    int*   bsum   = (int*)  take(512);
    int*   boff   = (int*)  take(512);
    int*   flags  = (int*)  take(256);
    float* invdeg = (float*)take((size_t)GN * 4);
    float* colsum = (float*)take(256 * 4);
    float* scsh   = (float*)take(256 * 4);
    float* biasf  = (float*)take(384 * 4);
    float* bf2    = (float*)take(128 * 4);
    float* bf3    = (float*)take(128 * 4);
    float* hb     = (float*)take(256);
    u16*   wf2    = (u16*)  take(32768 * 2);
    u16*   wf3    = (u16*)  take(32768 * 2);
    u16*   hwl    = (u16*)  take(128 * 2);
    u16*   hwr    = (u16*)  take(128 * 2);
    float* yv     = (float*)take((size_t)GN * 4);
    float* rv     = (float*)take((size_t)GN * 4);
    int*   col    = (int*)  take((size_t)GE * 4);
    u16*   xb     = (u16*)  take((size_t)GN * 128 * 2);
    u16*   amean  = (u16*)  take((size_t)GN * 128 * 2);
    u16*   hbuf   = (u16*)  take((size_t)GN * 128 * 2);
    u16*   wbuf   = (u16*)  take((size_t)WTOT * 2);

    const int NB_N = (GN + 255) / 256;          // 391
    const int NB_S = (GN + 1023) / 1024;        // 98
    const int NB_W = (GN + 3) / 4;              // 25000 (wave per node)
    const int NB_G = (GN + 127) / 128;          // 782
    const int NB_M = (GN * 16 + 255) / 256;     // 6250
    const int NB_C = (WTOT + 255) / 256;        // 390
    const int NB_E8 = ((GE + 1023) / 1024) * 8; // 12504 (8 residue replicas)

    k_init    <<<NB_N, 256, 0, stream>>>(ei, (const u32*)x, deg, colsum, flags);
    k_convx   <<<NB_M, 256, 0, stream>>>(x, flags, xb);
    k_convw   <<<NB_C, 256, 0, stream>>>(Wl, Wr, bias, gamma, beta, wlout, wrout, bout, flags, wbuf, biasf);
    k_count_sh<<<NB_E8, 256, 0, stream>>>(ei, flags, deg);
    k_scan1   <<<NB_S, 256, 0, stream>>>(deg, rowptr, bsum);
    k_scan2   <<<1,    128, 0, stream>>>(bsum, boff, rowptr);
    k_scan3   <<<NB_N, 256, 0, stream>>>(rowptr, cursor, deg, boff, invdeg);
    k_fill_sh <<<NB_E8, 256, 0, stream>>>(ei, flags, cursor, col);

    const u16* hin = xb;
    for (int i = 0; i < 3; ++i){
        const u16* Wli; const u16* Wri; const float* bfi;
        if (i == 0){ Wli = wbuf;     Wri = wbuf + WOFF_WR; bfi = biasf; }
        else if (i == 1){ Wli = wf2; Wri = wf2 + 16384;    bfi = bf2; }
        else { Wli = wf3;            Wri = wf3 + 16384;    bfi = bf3; }
        k_agg <<<NB_W, 256, 0, stream>>>(hin, rowptr, col, invdeg, amean);
        k_gemm<<<NB_G, 256, 0, stream>>>(amean, hin, Wli, Wri, bfi, hbuf, colsum);
        k_bn  <<<1,    256, 0, stream>>>(colsum, wbuf + WOFF_G + i * 128, wbuf + WOFF_BE + i * 128, scsh);
        if (i == 0)
            k_fold<<<65, 256, 0, stream>>>(scsh, wbuf + 16384, wbuf + WOFF_WR + 16384, biasf + 128, wf2, bf2);
        else if (i == 1)
            k_fold<<<65, 256, 0, stream>>>(scsh, wbuf + 32768, wbuf + WOFF_WR + 32768, biasf + 256, wf3, bf3);
        else
            k_hfold<<<1, 64, 0, stream>>>(scsh, wbuf + WOFF_WLO, wbuf + WOFF_WRO, wbuf + WOFF_BO, hwl, hwr, hb);
        hin = hbuf;
    }
    k_dot<<<NB_W, 256, 0, stream>>>(hbuf, hwl, hwr, yv, rv);
    k_out<<<NB_N, 256, 0, stream>>>(yv, rv, rowptr, col, invdeg, hb, flags, d_out);
}

// Round 6
// 630.910 us; speedup vs baseline: 1.4634x; 1.0834x over previous
//
#include <hip/hip_runtime.h>

typedef unsigned short u16;
typedef unsigned int u32;
typedef unsigned long long u64;

#define GN 100000
#define GE 1600000
#define DCAP 64        // padded CSR capacity per node (Poisson(16); P(>64) ~ 1e-20)

typedef __bf16 bf16x8 __attribute__((ext_vector_type(8)));
typedef float f32x4 __attribute__((ext_vector_type(4)));
typedef u32 u32x4 __attribute__((ext_vector_type(4)));

__device__ __forceinline__ float bl(u32 u){ return __uint_as_float(u << 16); }
__device__ __forceinline__ float bh(u32 u){ return __uint_as_float(u & 0xffff0000u); }
__device__ __forceinline__ float bfu(u16 v){ return __uint_as_float(((u32)v) << 16); }
__device__ __forceinline__ u16 f2bf(float f){
    u32 u = __float_as_uint(f);
    u32 r = (u + 0x7fffu + ((u >> 16) & 1u)) >> 16;
    return (u16)r;
}

// ---- init: zero cursor/colsum; detect edge int32/int64; detect x f32/bf16 ----
// flags[0]: 1 => edge_index int64; flags[1]: 1 => float tensors are f32
__global__ void __launch_bounds__(256) k_init(const int* ei, const u32* xraw,
                                              int* cursor, float* colsum, int* flags){
    int i = blockIdx.x * 256 + threadIdx.x;
    if (i < GN) cursor[i] = 0;
    int t = threadIdx.x;
    if (blockIdx.x == 0){
        __shared__ int s_any[4];
        colsum[t] = 0.f;
        int v = 0;
        #pragma unroll
        for (int j = 0; j < 4; ++j){
            int k = t * 4 + j;                // k in [0,1024)
            v |= ei[2 * k * 1000 + 1];        // dword pos <= 2046001 < 3.2M
        }
        #pragma unroll
        for (int m = 1; m < 64; m <<= 1) v |= __shfl_xor(v, m);
        if ((t & 63) == 0) s_any[t >> 6] = v;
        __syncthreads();
        if (t == 0){
            int any = s_any[0] | s_any[1] | s_any[2] | s_any[3];
            flags[0] = (any == 0) ? 1 : 0;
        }
    }
    if (blockIdx.x == 1){
        __shared__ int s_cnt[4];
        // low u16 of each dword: bf16 of ~N(0,1) has exponent in [100,140];
        // f32 mantissa bits hit that window ~16% of the time.
        int cnt = 0;
        #pragma unroll
        for (int j = 0; j < 4; ++j){
            int idx = (t * 4 + j) * 6000 + 3;     // < 6.15M dwords, safe both ways
            u32 u = xraw[idx];
            int e = (u >> 7) & 0xFF;
            cnt += (e >= 100 && e <= 140) ? 1 : 0;
        }
        #pragma unroll
        for (int m = 1; m < 64; m <<= 1) cnt += __shfl_xor(cnt, m);
        if ((t & 63) == 0) s_cnt[t >> 6] = cnt;
        __syncthreads();
        if (t == 0){
            int tot = s_cnt[0] + s_cnt[1] + s_cnt[2] + s_cnt[3];
            flags[1] = (tot > 512) ? 0 : 1;
        }
    }
}

// ---- convert x -> internal bf16 (copy if already bf16) ----
__global__ void __launch_bounds__(256) k_convx(const void* x, const int* flags, u16* xb){
    int gid = blockIdx.x * 256 + threadIdx.x;     // one 8-element chunk
    if (gid >= GN * 16) return;
    if (flags[1]){
        const u32x4* xf = (const u32x4*)x;
        u32x4 a = __builtin_nontemporal_load(xf + gid * 2);
        u32x4 b = __builtin_nontemporal_load(xf + gid * 2 + 1);
        u32x4 o;
        o.x = (u32)f2bf(__uint_as_float(a.x)) | ((u32)f2bf(__uint_as_float(a.y)) << 16);
        o.y = (u32)f2bf(__uint_as_float(a.z)) | ((u32)f2bf(__uint_as_float(a.w)) << 16);
        o.z = (u32)f2bf(__uint_as_float(b.x)) | ((u32)f2bf(__uint_as_float(b.y)) << 16);
        o.w = (u32)f2bf(__uint_as_float(b.z)) | ((u32)f2bf(__uint_as_float(b.w)) << 16);
        ((u32x4*)xb)[gid] = o;
    } else {
        ((u32x4*)xb)[gid] = __builtin_nontemporal_load((const u32x4*)x + gid);
    }
}

// ---- convert all params -> contiguous bf16 block (+ f32 copy of biases) ----
// layout: Wl[49152] | Wr[49152] | b[384] | gamma[384] | beta[384]
//         | wlout[128] | wrout[128] | bout[1]
#define WOFF_WR    49152
#define WOFF_B     98304
#define WOFF_G     98688
#define WOFF_BE    99072
#define WOFF_WLO   99456
#define WOFF_WRO   99584
#define WOFF_BO    99712
#define WTOT       99713
__global__ void __launch_bounds__(256) k_convw(const void* Wl, const void* Wr, const void* b,
                                               const void* g, const void* be, const void* wlo,
                                               const void* wro, const void* bo,
                                               const int* flags, u16* wbuf, float* biasf){
    int i = blockIdx.x * 256 + threadIdx.x;
    if (i >= WTOT) return;
    const void* s; int k;
    if      (i < WOFF_WR ){ s = Wl;  k = i; }
    else if (i < WOFF_B  ){ s = Wr;  k = i - WOFF_WR; }
    else if (i < WOFF_G  ){ s = b;   k = i - WOFF_B; }
    else if (i < WOFF_BE ){ s = g;   k = i - WOFF_G; }
    else if (i < WOFF_WLO){ s = be;  k = i - WOFF_BE; }
    else if (i < WOFF_WRO){ s = wlo; k = i - WOFF_WLO; }
    else if (i < WOFF_BO ){ s = wro; k = i - WOFF_WRO; }
    else                  { s = bo;  k = 0; }
    float fv = flags[1] ? ((const float*)s)[k] : bfu(((const u16*)s)[k]);
    wbuf[i] = f2bf(fv);
    if (i >= WOFF_B && i < WOFF_B + 384) biasf[i - WOFF_B] = fv;
}

// ---- XCD-sharded padded-CSR fill: block b handles edge chunk b>>3, commits
// only dsts whose 512-node range has residue b&7 (keeps each range's col
// window + cursor lines on one XCD). Non-temporal ei loads keep the edge
// stream from evicting those lines before they fill.
__global__ void __launch_bounds__(256) k_fill_sh(const int* ei, const int* flags,
                                                 int* cursor, int* col){
    int res = blockIdx.x & 7;
    int base = (blockIdx.x >> 3) * 1024;
    int is64 = flags[0];
    #pragma unroll
    for (int k = 0; k < 4; ++k){
        int e = base + k * 256 + threadIdx.x;
        if (e >= GE) continue;
        int s, d;
        if (is64){ d = __builtin_nontemporal_load(ei + 2 * (GE + e));
                   s = __builtin_nontemporal_load(ei + 2 * e); }
        else     { d = __builtin_nontemporal_load(ei + GE + e);
                   s = __builtin_nontemporal_load(ei + e); }
        if (((d >> 9) & 7) == res){
            int pos = atomicAdd(&cursor[d], 1);
            if (pos < DCAP) col[d * DCAP + pos] = s;
        }
    }
}

// ---- mean aggregation: one wave per node over padded CSR ----
__global__ void __launch_bounds__(256) k_agg(const u16* hin, const int* deg, const int* col,
                                             u16* amean){
    int wid = threadIdx.x >> 6, lane = threadIdx.x & 63;
    int node = blockIdx.x * 4 + wid;
    if (node >= GN) return;
    int d = deg[node];
    int cnt = d < DCAP ? d : DCAP;
    const int* nb = col + node * DCAP;
    const u32* h32 = (const u32*)hin;
    float lo = 0.f, hi = 0.f;
    int e = 0;
    for (; e + 7 < cnt; e += 8){
        u32 v0 = h32[nb[e]     * 64 + lane];
        u32 v1 = h32[nb[e + 1] * 64 + lane];
        u32 v2 = h32[nb[e + 2] * 64 + lane];
        u32 v3 = h32[nb[e + 3] * 64 + lane];
        u32 v4 = h32[nb[e + 4] * 64 + lane];
        u32 v5 = h32[nb[e + 5] * 64 + lane];
        u32 v6 = h32[nb[e + 6] * 64 + lane];
        u32 v7 = h32[nb[e + 7] * 64 + lane];
        lo += bl(v0) + bl(v1) + bl(v2) + bl(v3) + bl(v4) + bl(v5) + bl(v6) + bl(v7);
        hi += bh(v0) + bh(v1) + bh(v2) + bh(v3) + bh(v4) + bh(v5) + bh(v6) + bh(v7);
    }
    for (; e + 3 < cnt; e += 4){
        u32 v0 = h32[nb[e]     * 64 + lane];
        u32 v1 = h32[nb[e + 1] * 64 + lane];
        u32 v2 = h32[nb[e + 2] * 64 + lane];
        u32 v3 = h32[nb[e + 3] * 64 + lane];
        lo += bl(v0) + bl(v1) + bl(v2) + bl(v3);
        hi += bh(v0) + bh(v1) + bh(v2) + bh(v3);
    }
    for (; e < cnt; ++e){
        u32 v = h32[nb[e] * 64 + lane];
        lo += bl(v); hi += bh(v);
    }
    float inv = (d > 0) ? 1.f / (float)d : 0.f;
    lo *= inv; hi *= inv;
    u32 packed = (u32)f2bf(lo) | ((u32)f2bf(hi) << 16);
    ((u32*)amean)[node * 64 + lane] = packed;
}

// ---- fused GEMM: hout = relu([amean|hin] @ [Wl;Wr] + b), + BN column stats ----
__global__ void __launch_bounds__(256) k_gemm(const u16* amean, const u16* hin,
                                              const u16* Wl, const u16* Wr, const float* biasf,
                                              u16* hout, float* colsum){
    __shared__ __align__(16) u16 wlds[32768];  // [kc=32][c=128][8] bf16, 64KB
    int t = threadIdx.x;
    for (int idx = t; idx < 16384; idx += 256){
        int k = idx >> 7, c = idx & 127;
        wlds[((k >> 3) << 10) + (c << 3) + (k & 7)] = Wl[idx];
        int k2 = k + 128;
        wlds[((k2 >> 3) << 10) + (c << 3) + (k2 & 7)] = Wr[idx];
    }
    __syncthreads();
    int wid = t >> 6, lane = t & 63;
    int quad = lane >> 4, l15 = lane & 15;
    int r0 = blockIdx.x * 128 + wid * 32;
    int rowa = r0 + l15, rowb = rowa + 16;
    f32x4 acc[2][8];
    #pragma unroll
    for (int i = 0; i < 2; i++)
        #pragma unroll
        for (int j = 0; j < 8; j++) acc[i][j] = (f32x4){0.f, 0.f, 0.f, 0.f};

    #pragma unroll
    for (int s = 0; s < 8; ++s){
        const u16* A = (s < 4) ? amean : hin;
        int kk = ((s & 3) << 5) + (quad << 3);
        union { u32x4 u; bf16x8 v; } fa0, fa1;
        fa0.u = (rowa < GN) ? *(const u32x4*)(A + rowa * 128 + kk) : (u32x4){0,0,0,0};
        fa1.u = (rowb < GN) ? *(const u32x4*)(A + rowb * 128 + kk) : (u32x4){0,0,0,0};
        int kc = (s << 2) + quad;
        const u16* wb = &wlds[(kc << 10) + (l15 << 3)];
        #pragma unroll
        for (int cb = 0; cb < 8; ++cb){
            union { u32x4 u; bf16x8 v; } fb;
            fb.u = *(const u32x4*)(wb + (cb << 7));
            acc[0][cb] = __builtin_amdgcn_mfma_f32_16x16x32_bf16(fa0.v, fb.v, acc[0][cb], 0, 0, 0);
            acc[1][cb] = __builtin_amdgcn_mfma_f32_16x16x32_bf16(fa1.v, fb.v, acc[1][cb], 0, 0, 0);
        }
    }
    __syncthreads();                  // done reading wlds; reuse for stats
    float* sst = (float*)wlds;        // [256]: sum[128], sumsq[128]
    sst[t] = 0.f;
    __syncthreads();

    float bsv[8];
    #pragma unroll
    for (int cb = 0; cb < 8; cb++) bsv[cb] = biasf[cb * 16 + l15];

    #pragma unroll
    for (int cb = 0; cb < 8; cb++){
        float csum = 0.f, csq = 0.f;
        #pragma unroll
        for (int rb = 0; rb < 2; rb++){
            int rbase = r0 + rb * 16 + quad * 4;
            #pragma unroll
            for (int rr = 0; rr < 4; rr++){
                int row = rbase + rr;
                float v = acc[rb][cb][rr] + bsv[cb];
                v = fmaxf(v, 0.f);
                if (row < GN) hout[row * 128 + cb * 16 + l15] = f2bf(v);
                float vm = (row < GN) ? v : 0.f;
                csum += vm; csq += vm * vm;
            }
        }
        csum += __shfl_xor(csum, 16); csum += __shfl_xor(csum, 32);
        csq  += __shfl_xor(csq, 16);  csq  += __shfl_xor(csq, 32);
        if (quad == 0){
            atomicAdd(&sst[cb * 16 + l15], csum);
            atomicAdd(&sst[128 + cb * 16 + l15], csq);
        }
    }
    __syncthreads();
    atomicAdd(&colsum[t], sst[t]);
}

// ---- BN finalize: per-column scale/shift; re-zero colsum for next layer ----
__global__ void __launch_bounds__(256) k_bn(float* colsum, const u16* gamma, const u16* beta, float* scsh){
    int t = threadIdx.x;
    float s = 0.f, q = 0.f;
    if (t < 128){ s = colsum[t]; q = colsum[128 + t]; }
    __syncthreads();
    colsum[t] = 0.f;
    if (t < 128){
        const float invn = 1.f / (float)GN;
        float mean = s * invn;
        float var = fmaxf(q * invn - mean * mean, 0.f);
        float rstd = rsqrtf(var + 1e-5f);
        float g  = bfu(gamma[t]);
        float be = bfu(beta[t]);
        float sc = g * rstd;
        scsh[t] = sc;
        scsh[128 + t] = be - mean * sc;
    }
}

// ---- fold BN affine into next layer's weights: W' = diag(sc)W, b' = b + sh@(Wl+Wr) ----
__global__ void __launch_bounds__(256) k_fold(const float* scsh, const u16* Wls, const u16* Wrs,
                                              const float* bsrc, u16* wfd, float* bfd){
    int b = blockIdx.x, t = threadIdx.x;
    if (b < 64){
        int idx = b * 256 + t;            // 0..16383
        int k = idx >> 7;
        float sc = scsh[k];
        wfd[idx]         = f2bf(sc * bfu(Wls[idx]));
        wfd[16384 + idx] = f2bf(sc * bfu(Wrs[idx]));
    } else if (t < 128){
        float acc = bsrc[t];
        for (int k = 0; k < 128; ++k){
            float sh = scsh[128 + k];
            acc += sh * (bfu(Wls[k * 128 + t]) + bfu(Wrs[k * 128 + t]));
        }
        bfd[t] = acc;
    }
}

// ---- fold BN affine into the output head ----
__global__ void __launch_bounds__(64) k_hfold(const float* scsh, const u16* wlo, const u16* wro,
                                              const u16* bo, u16* hwl, u16* hwr, float* hb){
    int l = threadIdx.x;
    float contrib = 0.f;
    #pragma unroll
    for (int j = 0; j < 2; ++j){
        int t = l + j * 64;
        float sc = scsh[t], sh = scsh[128 + t];
        float wl = bfu(wlo[t]), wr = bfu(wro[t]);
        hwl[t] = f2bf(sc * wl);
        hwr[t] = f2bf(sc * wr);
        contrib += sh * (wl + wr);
    }
    #pragma unroll
    for (int m = 1; m < 64; m <<= 1) contrib += __shfl_xor(contrib, m);
    if (l == 0) hb[0] = contrib + bfu(bo[0]);
}

// ---- output head: y = h@Wl', r = h@Wr' (wave per node) ----
__global__ void __launch_bounds__(256) k_dot(const u16* h, const u16* wl, const u16* wr,
                                             float* y, float* r){
    int node = (blockIdx.x * 256 + threadIdx.x) >> 6;
    int lane = threadIdx.x & 63;
    if (node >= GN) return;
    u32 hv  = ((const u32*)h)[node * 64 + lane];
    u32 wlv = ((const u32*)wl)[lane];
    u32 wrv = ((const u32*)wr)[lane];
    float hlo = bl(hv), hhi = bh(hv);
    float ya = hlo * bl(wlv) + hhi * bh(wlv);
    float ra = hlo * bl(wrv) + hhi * bh(wrv);
    #pragma unroll
    for (int m = 1; m < 64; m <<= 1){ ya += __shfl_xor(ya, m); ra += __shfl_xor(ra, m); }
    if (lane == 0){ y[node] = ya; r[node] = ra; }
}

__global__ void __launch_bounds__(256) k_out(const float* y, const float* r, const int* deg,
                                             const int* col, const float* hb,
                                             const int* flags, void* out){
    int n = blockIdx.x * 256 + threadIdx.x;
    if (n >= GN) return;
    int d = deg[n];
    int cnt = d < DCAP ? d : DCAP;
    const int* nb = col + n * DCAP;
    float s = 0.f;
    for (int e = 0; e < cnt; ++e) s += y[nb[e]];
    float inv = (d > 0) ? 1.f / (float)d : 0.f;
    float z = inv * s + r[n] + hb[0];
    float sg = 1.f / (1.f + __expf(-z));
    if (flags[1]) ((float*)out)[n] = sg;
    else          ((u16*)out)[n] = f2bf(sg);
}

extern "C" void kernel_launch(void* const* d_in, const int* in_sizes, int n_in,
                              void* d_out, int out_size, void* d_ws, size_t ws_size,
                              hipStream_t stream) {
    const void* x     = d_in[0];
    const int*  ei    = (const int*)d_in[1];
    const void* Wl    = d_in[2];
    const void* Wr    = d_in[3];
    const void* bias  = d_in[4];
    const void* gamma = d_in[5];
    const void* beta  = d_in[6];
    const void* wlout = d_in[7];
    const void* wrout = d_in[8];
    const void* bout  = d_in[9];

    char* p = (char*)d_ws;
    auto take = [&](size_t b){ void* q = (void*)p; p += (b + 255) & ~(size_t)255; return q; };
    int*   cursor = (int*)  take((size_t)GN * 4);        // becomes deg after fill
    int*   flags  = (int*)  take(256);
    float* colsum = (float*)take(256 * 4);
    float* scsh   = (float*)take(256 * 4);
    float* biasf  = (float*)take(384 * 4);
    float* bf2    = (float*)take(128 * 4);
    float* bf3    = (float*)take(128 * 4);
    float* hb     = (float*)take(256);
    u16*   wf2    = (u16*)  take(32768 * 2);
    u16*   wf3    = (u16*)  take(32768 * 2);
    u16*   hwl    = (u16*)  take(128 * 2);
    u16*   hwr    = (u16*)  take(128 * 2);
    float* yv     = (float*)take((size_t)GN * 4);
    float* rv     = (float*)take((size_t)GN * 4);
    int*   col    = (int*)  take((size_t)GN * DCAP * 4); // padded CSR, 25.6 MB
    u16*   xb     = (u16*)  take((size_t)GN * 128 * 2);
    u16*   amean  = (u16*)  take((size_t)GN * 128 * 2);
    u16*   hbuf   = (u16*)  take((size_t)GN * 128 * 2);
    u16*   wbuf   = (u16*)  take((size_t)WTOT * 2);

    const int NB_N = (GN + 255) / 256;          // 391
    const int NB_W = (GN + 3) / 4;              // 25000 (wave per node)
    const int NB_G = (GN + 127) / 128;          // 782
    const int NB_M = (GN * 16 + 255) / 256;     // 6250
    const int NB_C = (WTOT + 255) / 256;        // 390
    const int NB_E8 = ((GE + 1023) / 1024) * 8; // 12504 (8 residue replicas)

    k_init   <<<NB_N, 256, 0, stream>>>(ei, (const u32*)x, cursor, colsum, flags);
    k_convx  <<<NB_M, 256, 0, stream>>>(x, flags, xb);
    k_convw  <<<NB_C, 256, 0, stream>>>(Wl, Wr, bias, gamma, beta, wlout, wrout, bout, flags, wbuf, biasf);
    k_fill_sh<<<NB_E8, 256, 0, stream>>>(ei, flags, cursor, col);

    const u16* hin = xb;
    for (int i = 0; i < 3; ++i){
        const u16* Wli; const u16* Wri; const float* bfi;
        if (i == 0){ Wli = wbuf;     Wri = wbuf + WOFF_WR; bfi = biasf; }
        else if (i == 1){ Wli = wf2; Wri = wf2 + 16384;    bfi = bf2; }
        else { Wli = wf3;            Wri = wf3 + 16384;    bfi = bf3; }
        k_agg <<<NB_W, 256, 0, stream>>>(hin, cursor, col, amean);
        k_gemm<<<NB_G, 256, 0, stream>>>(amean, hin, Wli, Wri, bfi, hbuf, colsum);
        k_bn  <<<1,    256, 0, stream>>>(colsum, wbuf + WOFF_G + i * 128, wbuf + WOFF_BE + i * 128, scsh);
        if (i == 0)
            k_fold<<<65, 256, 0, stream>>>(scsh, wbuf + 16384, wbuf + WOFF_WR + 16384, biasf + 128, wf2, bf2);
        else if (i == 1)
            k_fold<<<65, 256, 0, stream>>>(scsh, wbuf + 32768, wbuf + WOFF_WR + 32768, biasf + 256, wf3, bf3);
        else
            k_hfold<<<1, 64, 0, stream>>>(scsh, wbuf + WOFF_WLO, wbuf + WOFF_WRO, wbuf + WOFF_BO, hwl, hwr, hb);
        hin = hbuf;
    }
    k_dot<<<NB_W, 256, 0, stream>>>(hbuf, hwl, hwr, yv, rv);
    k_out<<<NB_N, 256, 0, stream>>>(yv, rv, cursor, col, hb, flags, d_out);
}